// Round 7
// baseline (471.737 us; speedup 1.0000x reference)
//
#include <hip/hip_runtime.h>
#include <hip/hip_bf16.h>
#include <stdint.h>

#define DIM 2048
#define NEXP 8
#define NTOK 8192
#define KSEL 6
#define NPAIR 28
#define SLOTS 92   // max sum of ceil(cnt_p/128) = 64 + 27, +1 safety

typedef short bf16x8 __attribute__((ext_vector_type(8)));
typedef unsigned short u16x8 __attribute__((ext_vector_type(8)));
typedef float f32x4 __attribute__((ext_vector_type(4)));
typedef const __attribute__((address_space(1))) unsigned int GU32;
typedef __attribute__((address_space(3))) unsigned int LU32;

// pair id p <-> (a,b), a<b: p = a*(15-a)/2 + (b-a-1)
static constexpr int PA[NPAIR] = {0,0,0,0,0,0,0,1,1,1,1,1,1,2,2,2,2,2,3,3,3,3,4,4,4,5,5,6};
static constexpr int PB[NPAIR] = {1,2,3,4,5,6,7,2,3,4,5,6,7,3,4,5,6,7,4,5,6,7,5,6,7,6,7,7};

__device__ __forceinline__ unsigned short f2b(float f) {
  union { float f; uint32_t u; } v; v.f = f;
  return (unsigned short)((v.u + 0x7fffu + ((v.u >> 16) & 1u)) >> 16);
}

// Fused independent front-end. Blocks [0, pairwBlocks): Wpair construction
// (streaming long pole, scheduled first). Blocks [pairwBlocks, +2048): gate.
__global__ __launch_bounds__(256) void gatepair_kernel(
    const float* __restrict__ x, const float* __restrict__ Wg,
    const float* __restrict__ bg, const float* __restrict__ We,
    unsigned short* __restrict__ xB, int* __restrict__ pid,
    unsigned short* __restrict__ Wp, int fbase, int frows, int pairwBlocks) {
  int bid = blockIdx.x;
  int t = threadIdx.x;
  if (bid < pairwBlocks) {
    // ---- pairw: Wp[p] = bf16(sum_e We[e] - We[a] - We[b]) ----
    size_t pos = ((size_t)bid * 256 + t) * 8;
    size_t src = (size_t)fbase * DIM + pos;
    float v[NEXP][8];
    float s[8];
#pragma unroll
    for (int i = 0; i < 8; ++i) s[i] = 0.f;
#pragma unroll
    for (int e = 0; e < NEXP; ++e) {
      float4 v0 = *(const float4*)(We + (size_t)e * DIM * DIM + src);
      float4 v1 = *(const float4*)(We + (size_t)e * DIM * DIM + src + 4);
      v[e][0] = v0.x; v[e][1] = v0.y; v[e][2] = v0.z; v[e][3] = v0.w;
      v[e][4] = v1.x; v[e][5] = v1.y; v[e][6] = v1.z; v[e][7] = v1.w;
#pragma unroll
      for (int i = 0; i < 8; ++i) s[i] += v[e][i];
    }
    size_t chunk = (size_t)frows * DIM;
#pragma unroll
    for (int pp = 0; pp < NPAIR; ++pp) {
      int a = PA[pp], b = PB[pp];
      u16x8 o;
#pragma unroll
      for (int i = 0; i < 8; ++i) o[i] = f2b(s[i] - v[a][i] - v[b][i]);
      *(u16x8*)(Wp + (size_t)pp * chunk + pos) = o;
    }
    return;
  }
  // ---- gate ----
  int w = t >> 6, l = t & 63;
  int n = (bid - pairwBlocks) * 4 + w;
  const float* xr = x + (size_t)n * DIM;
  float xv[32];
#pragma unroll
  for (int j = 0; j < 8; ++j) {
    float4 v = *(const float4*)(xr + 4 * l + 256 * j);
    xv[4 * j + 0] = v.x; xv[4 * j + 1] = v.y;
    xv[4 * j + 2] = v.z; xv[4 * j + 3] = v.w;
  }
  unsigned short* xbr = xB + (size_t)n * DIM;
#pragma unroll
  for (int j = 0; j < 8; ++j) {
    ushort4 o;
    o.x = f2b(xv[4 * j + 0]); o.y = f2b(xv[4 * j + 1]);
    o.z = f2b(xv[4 * j + 2]); o.w = f2b(xv[4 * j + 3]);
    *(ushort4*)(xbr + 4 * l + 256 * j) = o;
  }
  float sc[NEXP];
#pragma unroll
  for (int e = 0; e < NEXP; ++e) {
    const float* wr = Wg + e * DIM;
    float s = 0.f;
#pragma unroll
    for (int j = 0; j < 8; ++j) {
      float4 v = *(const float4*)(wr + 4 * l + 256 * j);
      s += xv[4 * j + 0] * v.x + xv[4 * j + 1] * v.y +
           xv[4 * j + 2] * v.z + xv[4 * j + 3] * v.w;
    }
#pragma unroll
    for (int off = 32; off > 0; off >>= 1) s += __shfl_xor(s, off, 64);
    sc[e] = s + bg[e];
  }
  if (l == 0) {
    int ex0 = -1, ex1 = -1;
#pragma unroll
    for (int e = 0; e < NEXP; ++e) {
      int rank = 0;
#pragma unroll
      for (int j = 0; j < NEXP; ++j)
        rank += (sc[j] > sc[e]) || (sc[j] == sc[e] && j < e);
      if (rank >= KSEL) { if (ex0 < 0) ex0 = e; else if (ex1 < 0) ex1 = e; }
    }
    pid[n] = ex0 * (15 - ex0) / 2 + (ex1 - ex0 - 1);
  }
}

// Standalone pairw (only used if workspace forces NR > 1).
__global__ __launch_bounds__(256) void pairw_kernel(
    const float* __restrict__ We, unsigned short* __restrict__ Wp,
    int fbase, int frows) {
  size_t pos = ((size_t)blockIdx.x * 256 + threadIdx.x) * 8;
  size_t src = (size_t)fbase * DIM + pos;
  float v[NEXP][8];
  float s[8];
#pragma unroll
  for (int i = 0; i < 8; ++i) s[i] = 0.f;
#pragma unroll
  for (int e = 0; e < NEXP; ++e) {
    float4 v0 = *(const float4*)(We + (size_t)e * DIM * DIM + src);
    float4 v1 = *(const float4*)(We + (size_t)e * DIM * DIM + src + 4);
    v[e][0] = v0.x; v[e][1] = v0.y; v[e][2] = v0.z; v[e][3] = v0.w;
    v[e][4] = v1.x; v[e][5] = v1.y; v[e][6] = v1.z; v[e][7] = v1.w;
#pragma unroll
    for (int i = 0; i < 8; ++i) s[i] += v[e][i];
  }
  size_t chunk = (size_t)frows * DIM;
#pragma unroll
  for (int pp = 0; pp < NPAIR; ++pp) {
    int a = PA[pp], b = PB[pp];
    u16x8 o;
#pragma unroll
    for (int i = 0; i < 8; ++i) o[i] = f2b(s[i] - v[a][i] - v[b][i]);
    *(u16x8*)(Wp + (size_t)pp * chunk + pos) = o;
  }
}

// Block 0: histogram (LDS atomics) -> cnt + slot->(p,m0) table -> scatter.
// Block 1: biasPair. No global atomics.
__global__ __launch_bounds__(1024) void bucket_kernel(
    const int* __restrict__ pid, const float* __restrict__ be,
    int* __restrict__ cnt, int* __restrict__ meta,
    int* __restrict__ slotP, int* __restrict__ slotM0,
    int* __restrict__ list, float* __restrict__ biasPair) {
  int t = threadIdx.x;
  if (blockIdx.x == 1) {
#pragma unroll
    for (int it = 0; it < 2; ++it) {
      int f = t + 1024 * it;
      float v[NEXP]; float s = 0.f;
#pragma unroll
      for (int e = 0; e < NEXP; ++e) { v[e] = be[e * DIM + f]; s += v[e]; }
#pragma unroll
      for (int pp = 0; pp < NPAIR; ++pp)
        biasPair[pp * DIM + f] = s - v[PA[pp]] - v[PB[pp]];
    }
    return;
  }
  __shared__ int lcnt[NPAIR];
  __shared__ int lpos[NPAIR];
  if (t < NPAIR) { lcnt[t] = 0; lpos[t] = 0; }
  __syncthreads();
  int p[8];
#pragma unroll
  for (int j = 0; j < 8; ++j) {
    p[j] = pid[t + 1024 * j];
    atomicAdd(&lcnt[p[j]], 1);
  }
  __syncthreads();
  if (t == 0) {
    int ts = 0;
    for (int q = 0; q < NPAIR; ++q) {
      cnt[q] = lcnt[q];
      for (int s0 = 0; s0 < lcnt[q]; s0 += 128) {
        slotP[ts] = q; slotM0[ts] = s0; ++ts;
      }
    }
    meta[0] = ts;
  }
  __syncthreads();
#pragma unroll
  for (int j = 0; j < 8; ++j) {
    int pos = atomicAdd(&lpos[p[j]], 1);
    list[p[j] * NTOK + pos] = t + 1024 * j;
  }
}

// Pair-bucket GEMM, 128(M)x256(N) tile, 8 waves (2x4), BK=64, 16x16x32 bf16
// MFMA, global_load_lds w=16, XOR bank swizzle — r6 geometry/epilogue
// unchanged. NEW: double-buffered LDS (96 KiB) + counted-vmcnt pipeline:
// STAGE(next->buf^1); s_waitcnt vmcnt(6) (waits only last iter's 6 loads,
// prefetch stays in flight a full iteration); raw s_barrier; ds_read+MFMA
// (setprio); s_barrier. Never vmcnt(0) in the main loop (T3/T4/T5).
__global__ __launch_bounds__(512, 2) void gemm_pair(
    const unsigned short* __restrict__ A, const unsigned short* __restrict__ Wp,
    const int* __restrict__ cnt, const int* __restrict__ list,
    const int* __restrict__ meta, const int* __restrict__ slotP,
    const int* __restrict__ slotM0, const float* __restrict__ biasPair,
    float* __restrict__ out, int fbase, int frows) {
  __shared__ unsigned short sA0[128 * 64];
  __shared__ unsigned short sA1[128 * 64];
  __shared__ unsigned short sB0[256 * 64];
  __shared__ unsigned short sB1[256 * 64];
  __shared__ int sRows[128];
  int total = meta[0];
  if (blockIdx.y >= total) return;
  int slot = total - 1 - blockIdx.y;   // reversed for LLC freshness
  int ft = blockIdx.x;
  int p = slotP[slot];
  int m0 = slotM0[slot];
  int c = cnt[p];

  int t = threadIdx.x;
  int w = t >> 6, l = t & 63;          // w in 0..7
  int wm = w >> 2, wn = w & 3;         // 2 (M) x 4 (N) wave grid
  int quad = l >> 4, lr = l & 15;
  int cs = (l & 7) ^ ((l >> 3) & 7);
  bool live = (wm == 0) || (m0 + 64 < c);  // dead M-half skip

  if (t < 128) {
    int idx = m0 + t;
    if (idx >= c) idx = c - 1;
    sRows[t] = list[p * NTOK + idx];
  }
  __syncthreads();

  size_t rowOffA[2], rowOffB[4];
#pragma unroll
  for (int i = 0; i < 2; ++i)
    rowOffA[i] = (size_t)sRows[i * 64 + w * 8 + (l >> 3)] * DIM;
  const unsigned short* Bb =
      Wp + (size_t)p * frows * DIM + (size_t)ft * 256 * DIM;
#pragma unroll
  for (int i = 0; i < 4; ++i)
    rowOffB[i] = (size_t)(i * 64 + w * 8 + (l >> 3)) * DIM;

  f32x4 acc[4][4];
#pragma unroll
  for (int mi = 0; mi < 4; ++mi)
#pragma unroll
    for (int ni = 0; ni < 4; ++ni) {
      acc[mi][ni][0] = 0.f; acc[mi][ni][1] = 0.f;
      acc[mi][ni][2] = 0.f; acc[mi][ni][3] = 0.f;
    }

#define STAGE(SAd, SBd, kk) do {                                              \
    _Pragma("unroll")                                                         \
    for (int i = 0; i < 2; ++i)                                               \
      __builtin_amdgcn_global_load_lds((GU32*)(A + rowOffA[i] + (kk) + cs * 8),\
          (LU32*)((SAd) + (i * 64 + w * 8) * 64), 16, 0, 0);                  \
    _Pragma("unroll")                                                         \
    for (int i = 0; i < 4; ++i)                                               \
      __builtin_amdgcn_global_load_lds((GU32*)(Bb + rowOffB[i] + (kk) + cs * 8),\
          (LU32*)((SBd) + (i * 64 + w * 8) * 64), 16, 0, 0);                  \
  } while (0)

#define COMPUTE(SAs, SBs) do {                                                \
    if (live) {                                                               \
      _Pragma("unroll")                                                       \
      for (int ks = 0; ks < 2; ++ks) {                                        \
        bf16x8 aF[4], bF[4];                                                  \
        _Pragma("unroll")                                                     \
        for (int mi = 0; mi < 4; ++mi)                                        \
          aF[mi] = *(const bf16x8*)((SAs) + (wm * 64 + mi * 16 + lr) * 64 +   \
                                    (((ks << 2) | quad) ^ (lr & 7)) * 8);     \
        _Pragma("unroll")                                                     \
        for (int ni = 0; ni < 4; ++ni)                                        \
          bF[ni] = *(const bf16x8*)((SBs) + (wn * 64 + ni * 16 + lr) * 64 +   \
                                    (((ks << 2) | quad) ^ (lr & 7)) * 8);     \
        __builtin_amdgcn_s_setprio(1);                                        \
        _Pragma("unroll")                                                     \
        for (int mi = 0; mi < 4; ++mi)                                        \
          _Pragma("unroll")                                                   \
          for (int ni = 0; ni < 4; ++ni)                                      \
            acc[mi][ni] = __builtin_amdgcn_mfma_f32_16x16x32_bf16(            \
                aF[mi], bF[ni], acc[mi][ni], 0, 0, 0);                        \
        __builtin_amdgcn_s_setprio(0);                                        \
      }                                                                       \
    }                                                                         \
  } while (0)

  // Prologue: tile 0 -> buf0.
  STAGE(sA0, sB0, 0);
  // 16 double-iterations: even tile in buf0, odd tile in buf1 (static bufs).
#pragma unroll 1
  for (int tt = 0; tt < 16; ++tt) {
    int k0 = tt * 128;
    // tile t0 = 2*tt (buf0): prefetch t0+1 -> buf1
    STAGE(sA1, sB1, k0 + 64);
    asm volatile("s_waitcnt vmcnt(6)" ::: "memory");
    __builtin_amdgcn_s_barrier();
    COMPUTE(sA0, sB0);
    __builtin_amdgcn_s_barrier();
    // tile t1 = 2*tt+1 (buf1): prefetch t1+1 -> buf0 (clamped on last)
    int kn = (tt < 15) ? k0 + 128 : k0 + 64;
    STAGE(sA0, sB0, kn);
    asm volatile("s_waitcnt vmcnt(6)" ::: "memory");
    __builtin_amdgcn_s_barrier();
    COMPUTE(sA1, sB1);
    __builtin_amdgcn_s_barrier();
  }
#undef STAGE
#undef COMPUTE

  if (!live) return;
  int f0 = fbase + ft * 256;
  float bb[4];
#pragma unroll
  for (int ni = 0; ni < 4; ++ni)
    bb[ni] = biasPair[p * DIM + f0 + wn * 64 + ni * 16 + lr];
#pragma unroll
  for (int mi = 0; mi < 4; ++mi) {
#pragma unroll
    for (int i = 0; i < 4; ++i) {
      int lrow = wm * 64 + mi * 16 + quad * 4 + i;
      if (m0 + lrow < c) {
        float* orow = out + (size_t)sRows[lrow] * DIM + f0;
#pragma unroll
        for (int ni = 0; ni < 4; ++ni)
          orow[wn * 64 + ni * 16 + lr] = acc[mi][ni][i] + bb[ni];
      }
    }
  }
}

extern "C" void kernel_launch(void* const* d_in, const int* in_sizes, int n_in,
                              void* d_out, int out_size, void* d_ws, size_t ws_size,
                              hipStream_t stream) {
  const float* x  = (const float*)d_in[0];
  const float* Wg = (const float*)d_in[1];
  const float* bg = (const float*)d_in[2];
  const float* We = (const float*)d_in[3];
  const float* be = (const float*)d_in[4];
  float* out = (float*)d_out;

  char* ws = (char*)d_ws;
  unsigned short* xB = (unsigned short*)ws; ws += (size_t)NTOK * DIM * 2;
  int* pid = (int*)ws;          ws += (size_t)NTOK * 4;
  int* cnt = (int*)ws;          ws += 128;
  int* meta = (int*)ws;         ws += 128;
  int* slotP = (int*)ws;        ws += 512;
  int* slotM0 = (int*)ws;       ws += 512;
  int* list = (int*)ws;         ws += (size_t)NPAIR * NTOK * 4;
  float* biasPair = (float*)ws; ws += (size_t)NPAIR * DIM * 4;
  unsigned short* Wp = (unsigned short*)ws;

  // NR=1 (full Wpair, 235 MB) when workspace permits; chunk only if forced.
  // frows must stay a multiple of 256 (gemm BN) -> NR <= 8.
  size_t avail = ws_size - (size_t)(ws - (char*)d_ws);
  int NR = 1;
  while (NR < 8 && (size_t)NPAIR * DIM * (size_t)(DIM / NR) * 2 > avail) NR <<= 1;
  int frows = DIM / NR;

  int pairwBlocks = (frows * DIM) / 2048;
  gatepair_kernel<<<pairwBlocks + NTOK / 4, 256, 0, stream>>>(
      x, Wg, bg, We, xB, pid, Wp, 0, frows, pairwBlocks);
  bucket_kernel<<<2, 1024, 0, stream>>>(pid, be, cnt, meta, slotP, slotM0,
                                        list, biasPair);
  gemm_pair<<<dim3(frows / 256, SLOTS), 512, 0, stream>>>(
      xB, Wp, cnt, list, meta, slotP, slotM0, biasPair, out, 0, frows);
  for (int r = 1; r < NR; ++r) {
    int fbase = r * frows;
    pairw_kernel<<<(frows * DIM) / 2048, 256, 0, stream>>>(We, Wp, fbase, frows);
    gemm_pair<<<dim3(frows / 256, SLOTS), 512, 0, stream>>>(
        xB, Wp, cnt, list, meta, slotP, slotM0, biasPair, out, fbase, frows);
  }
}